// Round 6
// baseline (827.587 us; speedup 1.0000x reference)
//
#include <hip/hip_runtime.h>
#include <cstdio>

typedef unsigned short u16;
typedef unsigned int u32;
typedef __attribute__((ext_vector_type(8))) short bf16x8;
typedef __attribute__((ext_vector_type(4))) float f32x4;

static constexpr int T = 8192;   // tokens = B*S
static constexpr int D = 1024;
static constexpr int F = 4096;
static constexpr int E = 8;

__device__ __forceinline__ u16 f2b(float f) {
  u32 u = __float_as_uint(f);
  u32 r = (u + 0x7fffu + ((u >> 16) & 1u)) >> 16;  // RNE
  return (u16)r;
}
__device__ __forceinline__ float b2f(u16 u) {
  return __uint_as_float(((u32)u) << 16);
}

// async global->LDS, 16B per lane (m104: dest = wave-uniform base + lane*16)
__device__ __forceinline__ void gload16(const void* g, void* l) {
  typedef const __attribute__((address_space(1))) void* gp_t;
  typedef __attribute__((address_space(3))) void* lp_t;
  __builtin_amdgcn_global_load_lds((gp_t)(uintptr_t)g, (lp_t)(uintptr_t)l, 16, 0, 0);
}

// ---------------- weight transpose + bf16 convert: [E][R][C] -> [E][C][R] ----------------
template<int R, int C>
__global__ void transpose_cvt_kernel(const float* __restrict__ in, u16* __restrict__ outp) {
  __shared__ float tile[64][65];
  const size_t base = (size_t)blockIdx.z * R * C;
  const int r0 = blockIdx.y * 64, c0 = blockIdx.x * 64;
  const int tx = threadIdx.x & 63, tg = threadIdx.x >> 6;
#pragma unroll
  for (int i = 0; i < 16; ++i) {
    int r = i * 4 + tg;
    tile[r][tx] = in[base + (size_t)(r0 + r) * C + (c0 + tx)];
  }
  __syncthreads();
  const int l32 = threadIdx.x & 31, g8 = threadIdx.x >> 5;
#pragma unroll
  for (int i = 0; i < 8; ++i) {
    int rp = i * 8 + g8;
    u16 v0 = f2b(tile[l32 * 2][rp]);
    u16 v1 = f2b(tile[l32 * 2 + 1][rp]);
    *(u32*)(outp + base + (size_t)(c0 + rp) * R + (r0 + l32 * 2)) = (u32)v0 | ((u32)v1 << 16);
  }
}

// ---------------- gate: logits (fp64), top-2, softmax, counts; also emits xb ----------------
__global__ void gate_kernel(const float* __restrict__ x, const float* __restrict__ gw,
                            u16* __restrict__ xb,
                            int* __restrict__ tki, float* __restrict__ tkw,
                            int* __restrict__ counts) {
  const int lane = threadIdx.x & 63;
  const int t = blockIdx.x * 4 + (threadIdx.x >> 6);
  const float* xr = x + (size_t)t * D + lane * 16;

  float xv[16];
#pragma unroll
  for (int i = 0; i < 4; ++i) {
    float4 v = ((const float4*)xr)[i];
    xv[i * 4 + 0] = v.x; xv[i * 4 + 1] = v.y; xv[i * 4 + 2] = v.z; xv[i * 4 + 3] = v.w;
  }
  union { u16 s[16]; uint4 q[2]; } pk;
#pragma unroll
  for (int j = 0; j < 16; ++j) pk.s[j] = f2b(xv[j]);
  uint4* xbo = (uint4*)(xb + (size_t)t * D + lane * 16);
  xbo[0] = pk.q[0]; xbo[1] = pk.q[1];

  double acc[8] = {0, 0, 0, 0, 0, 0, 0, 0};
  const float4* gwp = (const float4*)(gw + (size_t)(lane * 16) * 8);
#pragma unroll
  for (int j = 0; j < 16; ++j) {
    double xd = (double)xv[j];
    float4 g0 = gwp[j * 2], g1 = gwp[j * 2 + 1];
    acc[0] += xd * (double)g0.x; acc[1] += xd * (double)g0.y;
    acc[2] += xd * (double)g0.z; acc[3] += xd * (double)g0.w;
    acc[4] += xd * (double)g1.x; acc[5] += xd * (double)g1.y;
    acc[6] += xd * (double)g1.z; acc[7] += xd * (double)g1.w;
  }
#pragma unroll
  for (int s = 1; s < 64; s <<= 1) {
#pragma unroll
    for (int e = 0; e < 8; ++e) acc[e] += __shfl_xor(acc[e], s, 64);
  }
  if (lane == 0) {
    int i0 = 0; double l0 = acc[0];
#pragma unroll
    for (int e = 1; e < 8; ++e) if (acc[e] > l0) { l0 = acc[e]; i0 = e; }
    int i1 = -1; double l1 = -1e300;
#pragma unroll
    for (int e = 0; e < 8; ++e) if (e != i0 && acc[e] > l1) { l1 = acc[e]; i1 = e; }
    float w0 = (float)(1.0 / (1.0 + exp(l1 - l0)));  // softmax over {l0,l1}
    float w1f = 1.0f - w0;
    tki[t * 2] = i0; tki[t * 2 + 1] = i1;
    tkw[t * 2] = w0; tkw[t * 2 + 1] = w1f;
    atomicAdd(&counts[i0], 1);
    atomicAdd(&counts[i1], 1);
  }
}

// ---------------- offsets (exclusive prefix) ----------------
__global__ void offsets_kernel(const int* __restrict__ counts, int* __restrict__ offs,
                               int* __restrict__ cursors) {
  if (threadIdx.x == 0) {
    int s = 0;
    for (int e = 0; e < E; ++e) { offs[e] = s; cursors[e] = s; s += counts[e]; }
    offs[E] = s;
  }
}

// ---------------- build compact per-expert token lists ----------------
__global__ void build_lists_kernel(const int* __restrict__ tki, const float* __restrict__ tkw,
                                   int* __restrict__ cursors, int* __restrict__ lst,
                                   float* __restrict__ lsw) {
  int t = blockIdx.x * 256 + threadIdx.x;
#pragma unroll
  for (int j = 0; j < 2; ++j) {
    int e = tki[t * 2 + j];
    int p = atomicAdd(&cursors[e], 1);
    lst[p] = t;
    lsw[p] = tkw[t * 2 + j];
  }
}

// ---------------- grouped GEMM, 128x128 tile, BK=64, 4 waves, dbuf stage-early ----------------
// r2 structure (best measured) + double-buffer: per K-tile {STAGE next into buf^1;
// sched_barrier; ds_read+MFMA from buf; __syncthreads (vmcnt0+lgkm0 drain, covered
// cross-block at 2 blocks/CU)}. T2 swizzle via pre-swizzled global source (rule 21).
// n-major XCD chunking (T1). G1: silu -> bf16 h. G2(!G1): atomicAdd fp32 into out rows
// scattered by lst, scaled by lsw (fuses the old combine kernel).
template<int KD, int ND, bool G1>
__global__ __launch_bounds__(256, 4) void moe_gemm(
    const u16* __restrict__ Abase, const u16* __restrict__ Bt, u16* __restrict__ hOut,
    float* __restrict__ fOut,
    const int* __restrict__ offs, const int* __restrict__ lst,
    const float* __restrict__ lsw) {
  __shared__ u16 As[2][128 * 64];
  __shared__ u16 Bs[2][128 * 64];
  constexpr int NXT = ND / 128;
  const int e = blockIdx.z;
  const int off = offs[e];
  const int cnt = offs[e + 1] - off;
  const int nmAct = (cnt + 127) >> 7;
  const int act = nmAct * NXT;
  const int d = (int)blockIdx.y * NXT + (int)blockIdx.x;
  const int q8 = (act + 7) >> 3;
  if ((d >> 3) >= q8) return;
  const int lin = (d & 7) * q8 + (d >> 3);
  if (lin >= act) return;
  const int m0 = (lin % nmAct) * 128;   // n-major: XCD-neighbors share n0 (B-slice L2-resident)
  const int n0 = (lin / nmAct) * 128;
  if (m0 >= cnt) return;

  const int tid = threadIdx.x;
  const int lane = tid & 63;
  const int wave = tid >> 6;
  const int wm = wave >> 1;     // 0..1
  const int wn = wave & 1;      // 0..1

  // staging source byte offsets (pre-swizzled columns, rule 21)
  u32 asrc[4], bsrc[4];
  {
#pragma unroll
    for (int i = 0; i < 4; ++i) {
      const int linear = i * 256 + tid;
      const int row = linear >> 3;          // 0..127
      const int cb = (linear & 7) * 16;
      const int scb = cb ^ ((row & 7) << 4);
      int grow = m0 + row; if (grow >= cnt) grow = cnt - 1;
      u32 arow = G1 ? (u32)lst[off + grow] : (u32)(off + grow);
      asrc[i] = arow * (u32)(KD * 2) + (u32)scb;
      u32 brow = (u32)e * (u32)ND + (u32)(n0 + row);
      bsrc[i] = brow * (u32)(KD * 2) + (u32)scb;
    }
  }
  const char* Ac = (const char*)Abase;
  const char* Bc = (const char*)Bt;

  f32x4 acc[4][4];
#pragma unroll
  for (int i = 0; i < 4; ++i)
#pragma unroll
    for (int j = 0; j < 4; ++j) acc[i][j] = (f32x4){0.f, 0.f, 0.f, 0.f};

#define STAGE(c, kb) do { \
    _Pragma("unroll") \
    for (int i = 0; i < 4; ++i) { \
      gload16(Ac + asrc[i] + (kb), (char*)&As[c][0] + i * 4096 + tid * 16); \
      gload16(Bc + bsrc[i] + (kb), (char*)&Bs[c][0] + i * 4096 + tid * 16); \
    } } while (0)

  const int arow_r = wm * 64 + (lane & 15);
  const int brow_r = wn * 64 + (lane & 15);
  const int koff = (lane >> 4) * 16;

  constexpr int NT = KD / 64;
  STAGE(0, 0);
  __syncthreads();   // vmcnt(0)+lgkmcnt(0)+barrier: tile 0 visible

  for (int t = 0; t < NT; ++t) {
    const int c = t & 1;
    if (t + 1 < NT) {
      STAGE(c ^ 1, (u32)(t + 1) * 128);       // issue next tile into dead buffer
      __builtin_amdgcn_sched_barrier(0);      // keep stage ahead of reads
    }
    // B fragments once (8 b128), A fragments per-mf (2 b128) to bound liveness
    bf16x8 bfr[4][2];
#pragma unroll
    for (int nf = 0; nf < 4; ++nf) {
      const int row = brow_r + nf * 16;
      const char* p = (const char*)&Bs[c][0] + row * 128;
      const int sw = (row & 7) << 4;
#pragma unroll
      for (int ks = 0; ks < 2; ++ks)
        bfr[nf][ks] = *(const bf16x8*)(p + ((ks * 64 + koff) ^ sw));
    }
#pragma unroll
    for (int mf = 0; mf < 4; ++mf) {
      const int row = arow_r + mf * 16;
      const char* p = (const char*)&As[c][0] + row * 128;
      const int sw = (row & 7) << 4;
      bf16x8 af0 = *(const bf16x8*)(p + ((0 * 64 + koff) ^ sw));
      bf16x8 af1 = *(const bf16x8*)(p + ((1 * 64 + koff) ^ sw));
#pragma unroll
      for (int nf = 0; nf < 4; ++nf) {
        acc[mf][nf] = __builtin_amdgcn_mfma_f32_16x16x32_bf16(af0, bfr[nf][0], acc[mf][nf], 0, 0, 0);
        acc[mf][nf] = __builtin_amdgcn_mfma_f32_16x16x32_bf16(af1, bfr[nf][1], acc[mf][nf], 0, 0, 0);
      }
    }
    __syncthreads();  // drains stage DMA (overlapped under MFMA) + joins waves
  }

  // epilogue: C/D map col=lane&15, row=(lane>>4)*4+r
#pragma unroll
  for (int mf = 0; mf < 4; ++mf) {
#pragma unroll
    for (int r = 0; r < 4; ++r) {
      const int grow = m0 + wm * 64 + mf * 16 + (lane >> 4) * 4 + r;
      if (grow >= cnt) continue;
      if (G1) {
        u16* op = hOut + (size_t)(off + grow) * ND + n0 + wn * 64;
#pragma unroll
        for (int nf = 0; nf < 4; ++nf) {
          float v = acc[mf][nf][r];
          v = v / (1.f + __expf(-v));   // silu
          op[nf * 16 + (lane & 15)] = f2b(v);
        }
      } else {
        const int tok = lst[off + grow];
        const float wgt = lsw[off + grow];
        float* op = fOut + (size_t)tok * ND + n0 + wn * 64;
#pragma unroll
        for (int nf = 0; nf < 4; ++nf)
          atomicAdd(op + nf * 16 + (lane & 15), acc[mf][nf][r] * wgt);
      }
    }
  }
#undef STAGE
}

extern "C" void kernel_launch(void* const* d_in, const int* in_sizes, int n_in,
                              void* d_out, int out_size, void* d_ws, size_t ws_size,
                              hipStream_t stream) {
  const float* x  = (const float*)d_in[0];
  const float* gw = (const float*)d_in[1];
  const float* w1 = (const float*)d_in[2];
  const float* w2 = (const float*)d_in[3];
  float* outp = (float*)d_out;

  char* ws = (char*)d_ws;
  size_t o = 0;
  auto alloc = [&](size_t b) { size_t r = o; o += (b + 255) & ~(size_t)255; return r; };
  size_t counts_o = alloc(E * 4);
  size_t offs_o   = alloc((E + 1) * 4);
  size_t curs_o   = alloc(E * 4);
  size_t tki_o    = alloc((size_t)T * 2 * 4);
  size_t tkw_o    = alloc((size_t)T * 2 * 4);
  size_t lst_o    = alloc((size_t)T * 2 * 4);
  size_t lsw_o    = alloc((size_t)T * 2 * 4);
  size_t xb_o     = alloc((size_t)T * D * 2);
  size_t w1t_o    = alloc((size_t)E * D * F * 2);
  size_t w2t_o    = alloc((size_t)E * D * F * 2);
  size_t h_o      = alloc((size_t)T * 2 * F * 2);
  if (o > ws_size) {
    fprintf(stderr, "kernel_launch: ws too small (need %zu, have %zu)\n", o, ws_size);
    return;
  }

  int*   counts  = (int*)(ws + counts_o);
  int*   offs    = (int*)(ws + offs_o);
  int*   cursors = (int*)(ws + curs_o);
  int*   tki     = (int*)(ws + tki_o);
  float* tkw     = (float*)(ws + tkw_o);
  int*   lst     = (int*)(ws + lst_o);
  float* lsw     = (float*)(ws + lsw_o);
  u16*   xb      = (u16*)(ws + xb_o);
  u16*   w1t     = (u16*)(ws + w1t_o);
  u16*   w2t     = (u16*)(ws + w2t_o);
  u16*   h       = (u16*)(ws + h_o);

  hipMemsetAsync(counts, 0, E * 4, stream);
  hipMemsetAsync(outp, 0, (size_t)T * D * 4, stream);   // G2 accumulates atomically
  transpose_cvt_kernel<D, F><<<dim3(F / 64, D / 64, E), 256, 0, stream>>>(w1, w1t);
  transpose_cvt_kernel<F, D><<<dim3(D / 64, F / 64, E), 256, 0, stream>>>(w2, w2t);
  gate_kernel<<<T / 4, 256, 0, stream>>>(x, gw, xb, tki, tkw, counts);
  offsets_kernel<<<1, 64, 0, stream>>>(counts, offs, cursors);
  build_lists_kernel<<<T / 256, 256, 0, stream>>>(tki, tkw, cursors, lst, lsw);
  moe_gemm<D, F, true><<<dim3(F / 128, T / 128, E), 256, 0, stream>>>(
      xb, w1t, h, nullptr, offs, lst, lsw);
  moe_gemm<F, D, false><<<dim3(D / 128, T / 128, E), 256, 0, stream>>>(
      h, w2t, nullptr, outp, offs, lst, lsw);
}

// Round 7
// 742.753 us; speedup vs baseline: 1.1142x; 1.1142x over previous
//
#include <hip/hip_runtime.h>
#include <cstdio>

typedef unsigned short u16;
typedef unsigned int u32;
typedef __attribute__((ext_vector_type(8))) short bf16x8;
typedef __attribute__((ext_vector_type(4))) float f32x4;

static constexpr int T = 8192;   // tokens = B*S
static constexpr int D = 1024;
static constexpr int F = 4096;
static constexpr int E = 8;

__device__ __forceinline__ u16 f2b(float f) {
  u32 u = __float_as_uint(f);
  u32 r = (u + 0x7fffu + ((u >> 16) & 1u)) >> 16;  // RNE
  return (u16)r;
}
__device__ __forceinline__ float b2f(u16 u) {
  return __uint_as_float(((u32)u) << 16);
}

// async global->LDS, 16B per lane (m104: dest = wave-uniform base + lane*16)
__device__ __forceinline__ void gload16(const void* g, void* l) {
  typedef const __attribute__((address_space(1))) void* gp_t;
  typedef __attribute__((address_space(3))) void* lp_t;
  __builtin_amdgcn_global_load_lds((gp_t)(uintptr_t)g, (lp_t)(uintptr_t)l, 16, 0, 0);
}

// ---------------- weight transpose + bf16 convert, both weights in one launch ----------------
// z < E: w1 [D][F] -> w1t [F][D];  z >= E: w2 [F][D] -> w2t [D][F]
__global__ void transpose_cvt_both_kernel(const float* __restrict__ w1, u16* __restrict__ w1t,
                                          const float* __restrict__ w2, u16* __restrict__ w2t) {
  __shared__ float tile[64][65];
  const bool second = blockIdx.z >= E;
  const int ez = second ? (int)blockIdx.z - E : (int)blockIdx.z;
  const int R = second ? F : D;     // input rows
  const int C = second ? D : F;     // input cols
  const float* in = second ? w2 : w1;
  u16* outp = second ? w2t : w1t;
  const size_t base = (size_t)ez * D * F;
  const int r0 = blockIdx.y * 64, c0 = blockIdx.x * 64;
  if (r0 >= R || c0 >= C) return;
  const int tx = threadIdx.x & 63, tg = threadIdx.x >> 6;
#pragma unroll
  for (int i = 0; i < 16; ++i) {
    int r = i * 4 + tg;
    tile[r][tx] = in[base + (size_t)(r0 + r) * C + (c0 + tx)];
  }
  __syncthreads();
  const int l32 = threadIdx.x & 31, g8 = threadIdx.x >> 5;
#pragma unroll
  for (int i = 0; i < 8; ++i) {
    int rp = i * 8 + g8;
    u16 v0 = f2b(tile[l32 * 2][rp]);
    u16 v1 = f2b(tile[l32 * 2 + 1][rp]);
    *(u32*)(outp + base + (size_t)(c0 + rp) * R + (r0 + l32 * 2)) = (u32)v0 | ((u32)v1 << 16);
  }
}

// ---------------- gate: logits (fp64), top-2, softmax, counts; also emits xb ----------------
__global__ void gate_kernel(const float* __restrict__ x, const float* __restrict__ gw,
                            u16* __restrict__ xb,
                            int* __restrict__ tki, float* __restrict__ tkw,
                            int* __restrict__ counts) {
  const int lane = threadIdx.x & 63;
  const int t = blockIdx.x * 4 + (threadIdx.x >> 6);
  const float* xr = x + (size_t)t * D + lane * 16;

  float xv[16];
#pragma unroll
  for (int i = 0; i < 4; ++i) {
    float4 v = ((const float4*)xr)[i];
    xv[i * 4 + 0] = v.x; xv[i * 4 + 1] = v.y; xv[i * 4 + 2] = v.z; xv[i * 4 + 3] = v.w;
  }
  union { u16 s[16]; uint4 q[2]; } pk;
#pragma unroll
  for (int j = 0; j < 16; ++j) pk.s[j] = f2b(xv[j]);
  uint4* xbo = (uint4*)(xb + (size_t)t * D + lane * 16);
  xbo[0] = pk.q[0]; xbo[1] = pk.q[1];

  double acc[8] = {0, 0, 0, 0, 0, 0, 0, 0};
  const float4* gwp = (const float4*)(gw + (size_t)(lane * 16) * 8);
#pragma unroll
  for (int j = 0; j < 16; ++j) {
    double xd = (double)xv[j];
    float4 g0 = gwp[j * 2], g1 = gwp[j * 2 + 1];
    acc[0] += xd * (double)g0.x; acc[1] += xd * (double)g0.y;
    acc[2] += xd * (double)g0.z; acc[3] += xd * (double)g0.w;
    acc[4] += xd * (double)g1.x; acc[5] += xd * (double)g1.y;
    acc[6] += xd * (double)g1.z; acc[7] += xd * (double)g1.w;
  }
#pragma unroll
  for (int s = 1; s < 64; s <<= 1) {
#pragma unroll
    for (int e = 0; e < 8; ++e) acc[e] += __shfl_xor(acc[e], s, 64);
  }
  if (lane == 0) {
    int i0 = 0; double l0 = acc[0];
#pragma unroll
    for (int e = 1; e < 8; ++e) if (acc[e] > l0) { l0 = acc[e]; i0 = e; }
    int i1 = -1; double l1 = -1e300;
#pragma unroll
    for (int e = 0; e < 8; ++e) if (e != i0 && acc[e] > l1) { l1 = acc[e]; i1 = e; }
    float w0 = (float)(1.0 / (1.0 + exp(l1 - l0)));  // softmax over {l0,l1}
    float w1f = 1.0f - w0;
    tki[t * 2] = i0; tki[t * 2 + 1] = i1;
    tkw[t * 2] = w0; tkw[t * 2 + 1] = w1f;
    atomicAdd(&counts[i0], 1);
    atomicAdd(&counts[i1], 1);
  }
}

// ---------------- offsets (exclusive prefix) ----------------
__global__ void offsets_kernel(const int* __restrict__ counts, int* __restrict__ offs,
                               int* __restrict__ cursors) {
  if (threadIdx.x == 0) {
    int s = 0;
    for (int e = 0; e < E; ++e) { offs[e] = s; cursors[e] = s; s += counts[e]; }
    offs[E] = s;
  }
}

// ---------------- build compact per-expert token lists ----------------
__global__ void build_lists_kernel(const int* __restrict__ tki, const float* __restrict__ tkw,
                                   int* __restrict__ cursors, int* __restrict__ lst,
                                   float* __restrict__ lsw) {
  int t = blockIdx.x * 256 + threadIdx.x;
#pragma unroll
  for (int j = 0; j < 2; ++j) {
    int e = tki[t * 2 + j];
    int p = atomicAdd(&cursors[e], 1);
    lst[p] = t;
    lsw[p] = tkw[t * 2 + j];
  }
}

// ---------------- grouped GEMM, 128x128 tile, BK=64, 4 waves — r2 structure, occupancy-4 ----------------
// Single-buffer, two __syncthreads per K-tile (best measured structure; m114 cross-block
// overlap does the latency hiding). __launch_bounds__(256,4): 60+64acc = 124 unified regs
// -> 16 waves/CU = 4 blocks (LDS 32 KB allows 5). T2 swizzle via pre-swizzled global
// source (rule 21). n-major XCD chunking (T1). G1: silu -> bf16 h. G2: atomicAdd fp32
// into out rows scattered by lst, scaled by lsw (combine fused).
template<int KD, int ND, bool G1>
__global__ __launch_bounds__(256, 4) void moe_gemm(
    const u16* __restrict__ Abase, const u16* __restrict__ Bt, u16* __restrict__ hOut,
    float* __restrict__ fOut,
    const int* __restrict__ offs, const int* __restrict__ lst,
    const float* __restrict__ lsw) {
  __shared__ u16 As[128 * 64];
  __shared__ u16 Bs[128 * 64];
  constexpr int NXT = ND / 128;
  const int e = blockIdx.z;
  const int off = offs[e];
  const int cnt = offs[e + 1] - off;
  const int nmAct = (cnt + 127) >> 7;
  const int act = nmAct * NXT;
  const int d = (int)blockIdx.y * NXT + (int)blockIdx.x;
  const int q8 = (act + 7) >> 3;
  if ((d >> 3) >= q8) return;
  const int lin = (d & 7) * q8 + (d >> 3);
  if (lin >= act) return;
  const int m0 = (lin % nmAct) * 128;   // n-major: XCD-neighbors share n0 (B-slice L2-resident)
  const int n0 = (lin / nmAct) * 128;
  if (m0 >= cnt) return;

  const int tid = threadIdx.x;
  const int lane = tid & 63;
  const int wave = tid >> 6;
  const int wm = wave >> 1;     // 0..1
  const int wn = wave & 1;      // 0..1

  // staging source byte offsets (pre-swizzled columns, rule 21)
  u32 asrc[4], bsrc[4];
#pragma unroll
  for (int i = 0; i < 4; ++i) {
    const int linear = i * 256 + tid;
    const int row = linear >> 3;          // 0..127
    const int cb = (linear & 7) * 16;
    const int scb = cb ^ ((row & 7) << 4);
    int grow = m0 + row; if (grow >= cnt) grow = cnt - 1;
    u32 arow = G1 ? (u32)lst[off + grow] : (u32)(off + grow);
    asrc[i] = arow * (u32)(KD * 2) + (u32)scb;
    u32 brow = (u32)e * (u32)ND + (u32)(n0 + row);
    bsrc[i] = brow * (u32)(KD * 2) + (u32)scb;
  }
  const char* Ac = (const char*)Abase;
  const char* Bc = (const char*)Bt;

  f32x4 acc[4][4];
#pragma unroll
  for (int i = 0; i < 4; ++i)
#pragma unroll
    for (int j = 0; j < 4; ++j) acc[i][j] = (f32x4){0.f, 0.f, 0.f, 0.f};

  const int arow_r = wm * 64 + (lane & 15);
  const int brow_r = wn * 64 + (lane & 15);
  const int koff = (lane >> 4) * 16;

  for (int kt = 0; kt < KD / 64; ++kt) {
    const u32 kb = (u32)kt * 128;   // 64 bf16 = 128 bytes
    __syncthreads();
#pragma unroll
    for (int i = 0; i < 4; ++i) {
      gload16(Ac + asrc[i] + kb, (char*)As + i * 4096 + tid * 16);
      gload16(Bc + bsrc[i] + kb, (char*)Bs + i * 4096 + tid * 16);
    }
    __syncthreads();
#pragma unroll
    for (int ks = 0; ks < 2; ++ks) {
      const int kbyte = ks * 64 + koff;
      bf16x8 af[4], bfv[4];
#pragma unroll
      for (int mf = 0; mf < 4; ++mf) {
        const int row = arow_r + mf * 16;
        af[mf] = *(const bf16x8*)((const char*)As + row * 128 + (kbyte ^ ((row & 7) << 4)));
      }
#pragma unroll
      for (int nf = 0; nf < 4; ++nf) {
        const int row = brow_r + nf * 16;
        bfv[nf] = *(const bf16x8*)((const char*)Bs + row * 128 + (kbyte ^ ((row & 7) << 4)));
      }
#pragma unroll
      for (int mf = 0; mf < 4; ++mf)
#pragma unroll
        for (int nf = 0; nf < 4; ++nf)
          acc[mf][nf] = __builtin_amdgcn_mfma_f32_16x16x32_bf16(af[mf], bfv[nf], acc[mf][nf], 0, 0, 0);
    }
  }

  // epilogue: C/D map col=lane&15, row=(lane>>4)*4+r
#pragma unroll
  for (int mf = 0; mf < 4; ++mf) {
#pragma unroll
    for (int r = 0; r < 4; ++r) {
      const int grow = m0 + wm * 64 + mf * 16 + (lane >> 4) * 4 + r;
      if (grow >= cnt) continue;
      if (G1) {
        u16* op = hOut + (size_t)(off + grow) * ND + n0 + wn * 64;
#pragma unroll
        for (int nf = 0; nf < 4; ++nf) {
          float v = acc[mf][nf][r];
          v = v / (1.f + __expf(-v));   // silu
          op[nf * 16 + (lane & 15)] = f2b(v);
        }
      } else {
        const int tok = lst[off + grow];
        const float wgt = lsw[off + grow];
        float* op = fOut + (size_t)tok * ND + n0 + wn * 64;
#pragma unroll
        for (int nf = 0; nf < 4; ++nf)
          atomicAdd(op + nf * 16 + (lane & 15), acc[mf][nf][r] * wgt);
      }
    }
  }
}

extern "C" void kernel_launch(void* const* d_in, const int* in_sizes, int n_in,
                              void* d_out, int out_size, void* d_ws, size_t ws_size,
                              hipStream_t stream) {
  const float* x  = (const float*)d_in[0];
  const float* gw = (const float*)d_in[1];
  const float* w1 = (const float*)d_in[2];
  const float* w2 = (const float*)d_in[3];
  float* outp = (float*)d_out;

  char* ws = (char*)d_ws;
  size_t o = 0;
  auto alloc = [&](size_t b) { size_t r = o; o += (b + 255) & ~(size_t)255; return r; };
  size_t counts_o = alloc(E * 4);
  size_t offs_o   = alloc((E + 1) * 4);
  size_t curs_o   = alloc(E * 4);
  size_t tki_o    = alloc((size_t)T * 2 * 4);
  size_t tkw_o    = alloc((size_t)T * 2 * 4);
  size_t lst_o    = alloc((size_t)T * 2 * 4);
  size_t lsw_o    = alloc((size_t)T * 2 * 4);
  size_t xb_o     = alloc((size_t)T * D * 2);
  size_t w1t_o    = alloc((size_t)E * D * F * 2);
  size_t w2t_o    = alloc((size_t)E * D * F * 2);
  size_t h_o      = alloc((size_t)T * 2 * F * 2);
  if (o > ws_size) {
    fprintf(stderr, "kernel_launch: ws too small (need %zu, have %zu)\n", o, ws_size);
    return;
  }

  int*   counts  = (int*)(ws + counts_o);
  int*   offs    = (int*)(ws + offs_o);
  int*   cursors = (int*)(ws + curs_o);
  int*   tki     = (int*)(ws + tki_o);
  float* tkw     = (float*)(ws + tkw_o);
  int*   lst     = (int*)(ws + lst_o);
  float* lsw     = (float*)(ws + lsw_o);
  u16*   xb      = (u16*)(ws + xb_o);
  u16*   w1t     = (u16*)(ws + w1t_o);
  u16*   w2t     = (u16*)(ws + w2t_o);
  u16*   h       = (u16*)(ws + h_o);

  hipMemsetAsync(counts, 0, E * 4, stream);
  hipMemsetAsync(outp, 0, (size_t)T * D * 4, stream);   // G2 accumulates atomically
  transpose_cvt_both_kernel<<<dim3(F / 64, F / 64, 2 * E), 256, 0, stream>>>(w1, w1t, w2, w2t);
  gate_kernel<<<T / 4, 256, 0, stream>>>(x, gw, xb, tki, tkw, counts);
  offsets_kernel<<<1, 64, 0, stream>>>(counts, offs, cursors);
  build_lists_kernel<<<T / 256, 256, 0, stream>>>(tki, tkw, cursors, lst, lsw);
  moe_gemm<D, F, true><<<dim3(F / 128, T / 128, E), 256, 0, stream>>>(
      xb, w1t, h, nullptr, offs, lst, lsw);
  moe_gemm<F, D, false><<<dim3(D / 128, T / 128, E), 256, 0, stream>>>(
      h, w2t, nullptr, outp, offs, lst, lsw);
}

// Round 8
// 543.676 us; speedup vs baseline: 1.5222x; 1.3662x over previous
//
#include <hip/hip_runtime.h>
#include <cstdio>

typedef unsigned short u16;
typedef unsigned int u32;
typedef __attribute__((ext_vector_type(8))) short bf16x8;
typedef __attribute__((ext_vector_type(4))) float f32x4;

static constexpr int T = 8192;   // tokens = B*S
static constexpr int D = 1024;
static constexpr int F = 4096;
static constexpr int E = 8;

__device__ __forceinline__ u16 f2b(float f) {
  u32 u = __float_as_uint(f);
  u32 r = (u + 0x7fffu + ((u >> 16) & 1u)) >> 16;  // RNE
  return (u16)r;
}
__device__ __forceinline__ float b2f(u16 u) {
  return __uint_as_float(((u32)u) << 16);
}

// async global->LDS, 16B per lane (m104: dest = wave-uniform base + lane*16)
__device__ __forceinline__ void gload16(const void* g, void* l) {
  typedef const __attribute__((address_space(1))) void* gp_t;
  typedef __attribute__((address_space(3))) void* lp_t;
  __builtin_amdgcn_global_load_lds((gp_t)(uintptr_t)g, (lp_t)(uintptr_t)l, 16, 0, 0);
}

// ---------------- weight transpose + bf16 convert: [E][R][C] -> [E][C][R] ----------------
template<int R, int C>
__global__ void transpose_cvt_kernel(const float* __restrict__ in, u16* __restrict__ outp) {
  __shared__ float tile[64][65];
  const size_t base = (size_t)blockIdx.z * R * C;
  const int r0 = blockIdx.y * 64, c0 = blockIdx.x * 64;
  const int tx = threadIdx.x & 63, tg = threadIdx.x >> 6;
#pragma unroll
  for (int i = 0; i < 16; ++i) {
    int r = i * 4 + tg;
    tile[r][tx] = in[base + (size_t)(r0 + r) * C + (c0 + tx)];
  }
  __syncthreads();
  const int l32 = threadIdx.x & 31, g8 = threadIdx.x >> 5;
#pragma unroll
  for (int i = 0; i < 8; ++i) {
    int rp = i * 8 + g8;
    u16 v0 = f2b(tile[l32 * 2][rp]);
    u16 v1 = f2b(tile[l32 * 2 + 1][rp]);
    *(u32*)(outp + base + (size_t)(c0 + rp) * R + (r0 + l32 * 2)) = (u32)v0 | ((u32)v1 << 16);
  }
}

// ---------------- gate: logits (fp64), top-2, softmax; emits xb. NO atomics. ----------------
__global__ void gate_kernel(const float* __restrict__ x, const float* __restrict__ gw,
                            u16* __restrict__ xb,
                            int* __restrict__ tki, float* __restrict__ tkw) {
  const int lane = threadIdx.x & 63;
  const int t = blockIdx.x * 4 + (threadIdx.x >> 6);
  const float* xr = x + (size_t)t * D + lane * 16;

  float xv[16];
#pragma unroll
  for (int i = 0; i < 4; ++i) {
    float4 v = ((const float4*)xr)[i];
    xv[i * 4 + 0] = v.x; xv[i * 4 + 1] = v.y; xv[i * 4 + 2] = v.z; xv[i * 4 + 3] = v.w;
  }
  union { u16 s[16]; uint4 q[2]; } pk;
#pragma unroll
  for (int j = 0; j < 16; ++j) pk.s[j] = f2b(xv[j]);
  uint4* xbo = (uint4*)(xb + (size_t)t * D + lane * 16);
  xbo[0] = pk.q[0]; xbo[1] = pk.q[1];

  double acc[8] = {0, 0, 0, 0, 0, 0, 0, 0};
  const float4* gwp = (const float4*)(gw + (size_t)(lane * 16) * 8);
#pragma unroll
  for (int j = 0; j < 16; ++j) {
    double xd = (double)xv[j];
    float4 g0 = gwp[j * 2], g1 = gwp[j * 2 + 1];
    acc[0] += xd * (double)g0.x; acc[1] += xd * (double)g0.y;
    acc[2] += xd * (double)g0.z; acc[3] += xd * (double)g0.w;
    acc[4] += xd * (double)g1.x; acc[5] += xd * (double)g1.y;
    acc[6] += xd * (double)g1.z; acc[7] += xd * (double)g1.w;
  }
#pragma unroll
  for (int s = 1; s < 64; s <<= 1) {
#pragma unroll
    for (int e = 0; e < 8; ++e) acc[e] += __shfl_xor(acc[e], s, 64);
  }
  if (lane == 0) {
    int i0 = 0; double l0 = acc[0];
#pragma unroll
    for (int e = 1; e < 8; ++e) if (acc[e] > l0) { l0 = acc[e]; i0 = e; }
    int i1 = -1; double l1 = -1e300;
#pragma unroll
    for (int e = 0; e < 8; ++e) if (e != i0 && acc[e] > l1) { l1 = acc[e]; i1 = e; }
    float w0 = (float)(1.0 / (1.0 + exp(l1 - l0)));  // softmax over {l0,l1}
    float w1f = 1.0f - w0;
    tki[t * 2] = i0; tki[t * 2 + 1] = i1;
    tkw[t * 2] = w0; tkw[t * 2 + 1] = w1f;
  }
}

// ---------------- atomic-free routing: counts + scan + scatter, ONE block ----------------
// 1024 threads x 16 entries = T*2 = 16384 (t,j) pairs. Deterministic positions via
// wave shfl_up scan + cross-wave scan. Writes offs[9], lst, lsw.
__global__ __launch_bounds__(1024) void scan_build_kernel(
    const int* __restrict__ tki, const float* __restrict__ tkw,
    int* __restrict__ offs, int* __restrict__ lst, float* __restrict__ lsw) {
  const int tid = threadIdx.x;
  const int lane = tid & 63, wv = tid >> 6;   // 16 waves
  const int base = tid * 16;
  int e_loc[16]; float w_loc[16];
  int cnt[8] = {0, 0, 0, 0, 0, 0, 0, 0};
#pragma unroll
  for (int i = 0; i < 16; ++i) {
    e_loc[i] = tki[base + i];
    w_loc[i] = tkw[base + i];
    cnt[e_loc[i]]++;
  }
  __shared__ int wsum[8][16];
  int excl[8];
#pragma unroll
  for (int e = 0; e < 8; ++e) {
    int inc = cnt[e];
#pragma unroll
    for (int s = 1; s < 64; s <<= 1) {
      int u = __shfl_up(inc, s, 64);
      if (lane >= s) inc += u;
    }
    if (lane == 63) wsum[e][wv] = inc;
    excl[e] = inc - cnt[e];
  }
  __syncthreads();
  int wbase[8], tot[8];
#pragma unroll
  for (int e = 0; e < 8; ++e) {
    int sb = 0, st = 0;
    for (int w = 0; w < 16; ++w) { int v = wsum[e][w]; if (w < wv) sb += v; st += v; }
    wbase[e] = sb; tot[e] = st;
  }
  int eoffs[9]; eoffs[0] = 0;
#pragma unroll
  for (int e = 0; e < 8; ++e) eoffs[e + 1] = eoffs[e] + tot[e];
  if (tid == 0) {
#pragma unroll
    for (int e = 0; e <= 8; ++e) offs[e] = eoffs[e];
  }
  int pos[8];
#pragma unroll
  for (int e = 0; e < 8; ++e) pos[e] = eoffs[e] + wbase[e] + excl[e];
#pragma unroll
  for (int i = 0; i < 16; ++i) {
    int e = e_loc[i];
    int p = pos[e]++;
    lst[p] = (base + i) >> 1;   // token index
    lsw[p] = w_loc[i];
  }
}

// ---------------- grouped GEMM, 128x128 tile, BK=64, 4 waves — r2-exact structure ----------------
// Single-buffer, two __syncthreads per K-tile (best measured: 222 us). global_load_lds
// staging with pre-swizzled global source + swizzled ds_read (T2, rule 21).
// G1: silu -> bf16 h. G2(!G1): atomicAdd fp32 into out rows (combine fused).
template<int KD, int ND, bool G1>
__global__ __launch_bounds__(256, 2) void moe_gemm(
    const u16* __restrict__ Abase, const u16* __restrict__ Bt, u16* __restrict__ hOut,
    float* __restrict__ fOut,
    const int* __restrict__ offs, const int* __restrict__ lst,
    const float* __restrict__ lsw) {
  __shared__ u16 As[128 * 64];
  __shared__ u16 Bs[128 * 64];
  const int e = blockIdx.z;
  const int off = offs[e];
  const int cnt = offs[e + 1] - off;
  const int m0 = blockIdx.y * 128;
  if (m0 >= cnt) return;
  const int n0 = blockIdx.x * 128;
  const int tid = threadIdx.x;
  const int lane = tid & 63;
  const int wave = tid >> 6;
  const int wm = wave >> 1;     // 0..1
  const int wn = wave & 1;      // 0..1

  // staging source byte offsets (pre-swizzled columns, rule 21)
  u32 asrc[4], bsrc[4];
#pragma unroll
  for (int i = 0; i < 4; ++i) {
    const int linear = i * 256 + tid;
    const int row = linear >> 3;          // 0..127
    const int cb = (linear & 7) * 16;
    const int scb = cb ^ ((row & 7) << 4);
    int grow = m0 + row; if (grow >= cnt) grow = cnt - 1;
    u32 arow = G1 ? (u32)lst[off + grow] : (u32)(off + grow);
    asrc[i] = arow * (u32)(KD * 2) + (u32)scb;
    u32 brow = (u32)e * (u32)ND + (u32)(n0 + row);
    bsrc[i] = brow * (u32)(KD * 2) + (u32)scb;
  }
  const char* Ac = (const char*)Abase;
  const char* Bc = (const char*)Bt;

  f32x4 acc[4][4];
#pragma unroll
  for (int i = 0; i < 4; ++i)
#pragma unroll
    for (int j = 0; j < 4; ++j) acc[i][j] = (f32x4){0.f, 0.f, 0.f, 0.f};

  const int arow_r = wm * 64 + (lane & 15);
  const int brow_r = wn * 64 + (lane & 15);
  const int koff = (lane >> 4) * 16;

  for (int kt = 0; kt < KD / 64; ++kt) {
    const u32 kb = (u32)kt * 128;   // 64 bf16 = 128 bytes
    __syncthreads();
#pragma unroll
    for (int i = 0; i < 4; ++i) {
      gload16(Ac + asrc[i] + kb, (char*)As + i * 4096 + tid * 16);
      gload16(Bc + bsrc[i] + kb, (char*)Bs + i * 4096 + tid * 16);
    }
    __syncthreads();
#pragma unroll
    for (int ks = 0; ks < 2; ++ks) {
      const int kbyte = ks * 64 + koff;
      bf16x8 af[4], bfv[4];
#pragma unroll
      for (int mf = 0; mf < 4; ++mf) {
        const int row = arow_r + mf * 16;
        af[mf] = *(const bf16x8*)((const char*)As + row * 128 + (kbyte ^ ((row & 7) << 4)));
      }
#pragma unroll
      for (int nf = 0; nf < 4; ++nf) {
        const int row = brow_r + nf * 16;
        bfv[nf] = *(const bf16x8*)((const char*)Bs + row * 128 + (kbyte ^ ((row & 7) << 4)));
      }
#pragma unroll
      for (int mf = 0; mf < 4; ++mf)
#pragma unroll
        for (int nf = 0; nf < 4; ++nf)
          acc[mf][nf] = __builtin_amdgcn_mfma_f32_16x16x32_bf16(af[mf], bfv[nf], acc[mf][nf], 0, 0, 0);
    }
  }

  // epilogue: C/D map col=lane&15, row=(lane>>4)*4+r
#pragma unroll
  for (int mf = 0; mf < 4; ++mf) {
#pragma unroll
    for (int r = 0; r < 4; ++r) {
      const int grow = m0 + wm * 64 + mf * 16 + (lane >> 4) * 4 + r;
      if (grow >= cnt) continue;
      if (G1) {
        u16* op = hOut + (size_t)(off + grow) * ND + n0 + wn * 64;
#pragma unroll
        for (int nf = 0; nf < 4; ++nf) {
          float v = acc[mf][nf][r];
          v = v / (1.f + __expf(-v));   // silu
          op[nf * 16 + (lane & 15)] = f2b(v);
        }
      } else {
        const int tok = lst[off + grow];
        const float wgt = lsw[off + grow];
        float* op = fOut + (size_t)tok * ND + n0 + wn * 64;
#pragma unroll
        for (int nf = 0; nf < 4; ++nf)
          atomicAdd(op + nf * 16 + (lane & 15), acc[mf][nf][r] * wgt);
      }
    }
  }
}

extern "C" void kernel_launch(void* const* d_in, const int* in_sizes, int n_in,
                              void* d_out, int out_size, void* d_ws, size_t ws_size,
                              hipStream_t stream) {
  const float* x  = (const float*)d_in[0];
  const float* gw = (const float*)d_in[1];
  const float* w1 = (const float*)d_in[2];
  const float* w2 = (const float*)d_in[3];
  float* outp = (float*)d_out;

  char* ws = (char*)d_ws;
  size_t o = 0;
  auto alloc = [&](size_t b) { size_t r = o; o += (b + 255) & ~(size_t)255; return r; };
  size_t offs_o   = alloc((E + 1) * 4);
  size_t tki_o    = alloc((size_t)T * 2 * 4);
  size_t tkw_o    = alloc((size_t)T * 2 * 4);
  size_t lst_o    = alloc((size_t)T * 2 * 4);
  size_t lsw_o    = alloc((size_t)T * 2 * 4);
  size_t xb_o     = alloc((size_t)T * D * 2);
  size_t w1t_o    = alloc((size_t)E * D * F * 2);
  size_t w2t_o    = alloc((size_t)E * D * F * 2);
  size_t h_o      = alloc((size_t)T * 2 * F * 2);
  if (o > ws_size) {
    fprintf(stderr, "kernel_launch: ws too small (need %zu, have %zu)\n", o, ws_size);
    return;
  }

  int*   offs    = (int*)(ws + offs_o);
  int*   tki     = (int*)(ws + tki_o);
  float* tkw     = (float*)(ws + tkw_o);
  int*   lst     = (int*)(ws + lst_o);
  float* lsw     = (float*)(ws + lsw_o);
  u16*   xb      = (u16*)(ws + xb_o);
  u16*   w1t     = (u16*)(ws + w1t_o);
  u16*   w2t     = (u16*)(ws + w2t_o);
  u16*   h       = (u16*)(ws + h_o);

  hipMemsetAsync(outp, 0, (size_t)T * D * 4, stream);   // G2 accumulates atomically
  transpose_cvt_kernel<D, F><<<dim3(F / 64, D / 64, E), 256, 0, stream>>>(w1, w1t);
  transpose_cvt_kernel<F, D><<<dim3(D / 64, F / 64, E), 256, 0, stream>>>(w2, w2t);
  gate_kernel<<<T / 4, 256, 0, stream>>>(x, gw, xb, tki, tkw);
  scan_build_kernel<<<1, 1024, 0, stream>>>(tki, tkw, offs, lst, lsw);
  moe_gemm<D, F, true><<<dim3(F / 128, T / 128, E), 256, 0, stream>>>(
      xb, w1t, h, nullptr, offs, lst, lsw);
  moe_gemm<F, D, false><<<dim3(D / 128, T / 128, E), 256, 0, stream>>>(
      h, w2t, nullptr, outp, offs, lst, lsw);
}